// Round 5
// baseline (1203.851 us; speedup 1.0000x reference)
//
#include <hip/hip_runtime.h>
#include <hip/hip_fp16.h>
#include <math.h>

#define Bn 32
#define Tn 64
#define Fdim 32
#define Gdim 32
#define Hdim 256
#define Ndim 20000
#define Cdim 32
#define G4 1024      // 4*H
#define BT 2048      // B*T
#define EPSc 1e-5f

__device__ __forceinline__ float sigmoidf_(float x){ return 1.0f/(1.0f + __expf(-x)); }
__device__ __forceinline__ float tanhf_(float x){ return 2.0f/(1.0f+__expf(-2.0f*x)) - 1.0f; }

typedef _Float16 h2t __attribute__((ext_vector_type(2)));

__device__ __forceinline__ float fdot2_(unsigned w, unsigned h, float acc){
#if defined(__has_builtin) && __has_builtin(__builtin_amdgcn_fdot2)
  return __builtin_amdgcn_fdot2(__builtin_bit_cast(h2t, w), __builtin_bit_cast(h2t, h), acc, false);
#else
  h2t a = __builtin_bit_cast(h2t, w), b = __builtin_bit_cast(h2t, h);
  acc = fmaf((float)a.x, (float)b.x, acc);
  return fmaf((float)a.y, (float)b.y, acc);
#endif
}

__device__ __forceinline__ unsigned packh_(float lo, float hi){
  unsigned ulo = (unsigned)__half_as_ushort(__float2half(lo));
  unsigned uhi = (unsigned)__half_as_ushort(__float2half(hi));
  return ulo | (uhi << 16);
}

__device__ __forceinline__ float unpk_(unsigned d, int odd){
  h2t p = __builtin_bit_cast(h2t, d);
  return odd ? (float)p.y : (float)p.x;
}

// ---- init workspace stats + lookup table -------------------------------
__global__ void init_kernel(float* ws){
  int i = blockIdx.x*256 + threadIdx.x;
  if (i < 2112) ws[i] = 0.0f;                  // gat stats (64) + bn stats (4*512)
  int* table = (int*)(ws + 2112);
  if (i < 40000) table[i] = 0x7fffffff;
}

// ---- gat_output mean/var reduction (float4 loads) ----------------------
__global__ void bn_stats_kernel(const float* __restrict__ gat, float* __restrict__ sums){
  __shared__ float ss[256], sq[256];
  int tid = threadIdx.x;
  int idx = blockIdx.x*256 + tid;
  int stride = gridDim.x*256;
  const int total4 = Bn*Ndim*Gdim/4; // 5,120,000 float4s
  const float4* g4 = (const float4*)gat;
  float s=0.f,q=0.f;
  for (int i=idx; i<total4; i+=stride){
    float4 v = g4[i];
    s += v.x+v.y+v.z+v.w;
    q += v.x*v.x + v.y*v.y + v.z*v.z + v.w*v.w;
  }
  ss[tid]=s; sq[tid]=q; __syncthreads();
  for (int off=128; off>=32; off>>=1){
    if(tid<off){ ss[tid]+=ss[tid+off]; sq[tid]+=sq[tid+off]; }
    __syncthreads();
  }
  // NOTE: per-g stats need per-channel sums; float4 spans 4 consecutive g.
  // Channels are preserved because Gdim=32 and lane strides keep g%4 = const
  // per component: i-th float4 covers g = (4i)%32..(4i+3)%32; component c has
  // g%4 == c only when... NOT per-channel!  -> handled below: we accumulate
  // per-component partial sums instead.
  if (tid<32){ atomicAdd(&sums[tid], ss[tid]); atomicAdd(&sums[32+tid], sq[tid]); }
}
// The above would be wrong for per-channel stats; replaced by a correct
// per-channel version:
__global__ void bn_stats_kernel2(const float* __restrict__ gat, float* __restrict__ sums){
  __shared__ float ss[256], sq[256];
  int tid = threadIdx.x;
  int lane8 = tid & 7;            // which float4-of-row (8 float4 per 32-ch row)
  int idx = blockIdx.x*256 + tid;
  int stride = gridDim.x*256;
  const int total4 = Bn*Ndim*Gdim/4;
  const float4* g4 = (const float4*)gat;
  float4 s = make_float4(0.f,0.f,0.f,0.f), q = make_float4(0.f,0.f,0.f,0.f);
  for (int i=idx; i<total4; i+=stride){
    float4 v = g4[i];
    s.x+=v.x; s.y+=v.y; s.z+=v.z; s.w+=v.w;
    q.x+=v.x*v.x; q.y+=v.y*v.y; q.z+=v.z*v.z; q.w+=v.w*v.w;
  }
  // threads with equal (tid&7) cover the same 4 channels (g0=4*(tid&7))
  ss[tid]=s.x; sq[tid]=q.x; __syncthreads();
  for (int off=128; off>=8; off>>=1){ if(tid<off){ ss[tid]+=ss[tid+off]; sq[tid]+=sq[tid+off]; } __syncthreads(); }
  if (tid<8){ atomicAdd(&sums[4*tid+0], ss[tid]); atomicAdd(&sums[32+4*tid+0], sq[tid]); }
  __syncthreads();
  ss[tid]=s.y; sq[tid]=q.y; __syncthreads();
  for (int off=128; off>=8; off>>=1){ if(tid<off){ ss[tid]+=ss[tid+off]; sq[tid]+=sq[tid+off]; } __syncthreads(); }
  if (tid<8){ atomicAdd(&sums[4*tid+1], ss[tid]); atomicAdd(&sums[32+4*tid+1], sq[tid]); }
  __syncthreads();
  ss[tid]=s.z; sq[tid]=q.z; __syncthreads();
  for (int off=128; off>=8; off>>=1){ if(tid<off){ ss[tid]+=ss[tid+off]; sq[tid]+=sq[tid+off]; } __syncthreads(); }
  if (tid<8){ atomicAdd(&sums[4*tid+2], ss[tid]); atomicAdd(&sums[32+4*tid+2], sq[tid]); }
  __syncthreads();
  ss[tid]=s.w; sq[tid]=q.w; __syncthreads();
  for (int off=128; off>=8; off>>=1){ if(tid<off){ ss[tid]+=ss[tid+off]; sq[tid]+=sq[tid+off]; } __syncthreads(); }
  if (tid<8){ atomicAdd(&sums[4*tid+3], ss[tid]); atomicAdd(&sums[32+4*tid+3], sq[tid]); }
}

// ---- node id -> first index table --------------------------------------
__global__ void table_kernel(const int* __restrict__ node_ids, int* __restrict__ table){
  int i = blockIdx.x*256 + threadIdx.x;
  if (i < Ndim) atomicMin(&table[node_ids[i]], i);
}

// ---- gather + normalize + concat -> lstm_in packed f16 (BT,32 pairs) ---
__global__ void build_input_kernel(const float* __restrict__ feats, const float* __restrict__ gat,
    const int* __restrict__ row_ids, const int* __restrict__ table, const float* __restrict__ sums,
    const float* __restrict__ bng, const float* __restrict__ bnb, unsigned* __restrict__ out){
  int gt = blockIdx.x*256 + threadIdx.x;     // BT*32 total
  int pos = gt >> 5; int k2 = gt & 31;
  float lo, hi;
  if (k2 < 16){
    float2 v = *(const float2*)(feats + pos*Fdim + 2*k2);
    lo = v.x; hi = v.y;
  } else {
    int g0 = 2*(k2-16);
    int r = row_ids[pos];
    int idx = table[r];
    if (idx < Ndim){
      int b = pos / Tn;
      float2 x = *(const float2*)(gat + (size_t)(b*Ndim + idx)*Gdim + g0);
      const float cnt = (float)(Bn*Ndim);
      float m0 = sums[g0]/cnt,   v0 = sums[32+g0]/cnt - m0*m0;
      float m1 = sums[g0+1]/cnt, v1 = sums[32+g0+1]/cnt - m1*m1;
      lo = (x.x-m0)*bng[g0]*rsqrtf(v0+EPSc) + bnb[g0];
      hi = (x.y-m1)*bng[g0+1]*rsqrtf(v1+EPSc) + bnb[g0+1];
    } else { lo = 0.0f; hi = 0.0f; }
  }
  out[gt] = packh_(lo, hi);
}

// ---- pack+transpose Wih (1024,K) fp32 -> (K/2,1024) f16 pairs ----------
struct TArgs { const float* src[8]; unsigned* dst[8]; int K[8]; };
__global__ void packwih_kernel(TArgs a){
  __shared__ unsigned tile[32][33];
  int mat = blockIdx.y;
  int K = a.K[mat];
  int K2 = K >> 1;
  int ktiles = K2 >> 5;                  // 1 (K=64) or 4 (K=256)
  int tk = blockIdx.x & 3;               // k2-tile
  int tn = blockIdx.x >> 2;              // n-tile 0..31
  if (tk >= ktiles) return;
  const float* src = a.src[mat];
  unsigned* dst = a.dst[mat];
  int tx = threadIdx.x, ty = threadIdx.y;   // 32 x 8
  int n0 = tn*32, k2_0 = tk*32;
  #pragma unroll
  for (int i=0;i<4;i++){
    int nn = ty + 8*i;
    const float* p = src + (size_t)(n0+nn)*K + 2*(k2_0 + tx);
    tile[nn][tx] = packh_(p[0], p[1]);
  }
  __syncthreads();
  #pragma unroll
  for (int i=0;i<4;i++){
    int r = ty + 8*i;  // local k2
    dst[(size_t)(k2_0 + r)*G4 + n0 + tx] = tile[tx][r];
  }
}

// ---- pack Whh matrices (1024,256) fp32 -> f16 pair-packed layout -------
struct PkArgs { const float* src[8]; };
__global__ void pack_kernel(PkArgs a, unsigned* __restrict__ dst){
  int gid = blockIdx.x*256 + threadIdx.x;   // 8*131072 total
  int m = gid >> 17;
  int rem = gid & 0x1FFFF;
  int q = rem & 3;
  int t2 = (rem >> 2) & 1023;
  int ci = rem >> 12;
  int c = ci >> 3, i = ci & 7;
  int j = t2 & 255, kq = t2 >> 8;
  int r = 4*j + c;
  int k = kq*64 + 8*i + 2*q;
  const float* W = a.src[m];
  dst[gid] = packh_(W[r*256 + k], W[r*256 + k + 1]);
}

// ---- input projection: out(m,1024) = x(m,K) @ WT(K,1024) + bias --------
struct PArgs { const unsigned* x[3]; const unsigned* wt[3]; const float* bias[3]; float* out[3]; int K2; };
__global__ __launch_bounds__(256) void proj_kernel(PArgs a){
  int hd = blockIdx.z;
  int n  = blockIdx.y*256 + threadIdx.x;
  int m0 = blockIdx.x*8;
  int K2 = a.K2;
  const unsigned* xh = a.x[hd] + (size_t)m0*K2;
  const unsigned* wt = a.wt[hd];
  float bv = a.bias[hd][n];
  float acc[8];
  #pragma unroll
  for (int i=0;i<8;i++) acc[i]=bv;
  for (int k2=0;k2<K2;k2+=4){
    unsigned w0 = wt[(size_t)(k2+0)*G4+n];
    unsigned w1 = wt[(size_t)(k2+1)*G4+n];
    unsigned w2 = wt[(size_t)(k2+2)*G4+n];
    unsigned w3 = wt[(size_t)(k2+3)*G4+n];
    #pragma unroll
    for (int i=0;i<8;i++){
      uint4 xv = *(const uint4*)(xh + i*K2 + k2);   // uniform -> s_load_dwordx4
      acc[i]=fdot2_(w0,xv.x,acc[i]); acc[i]=fdot2_(w1,xv.y,acc[i]);
      acc[i]=fdot2_(w2,xv.z,acc[i]); acc[i]=fdot2_(w3,xv.w,acc[i]);
    }
  }
  float* out = a.out[hd] + (size_t)m0*G4 + n;
  #pragma unroll
  for (int i=0;i<8;i++) out[i*G4]=acc[i];
}

// ---- LSTM recurrence: one block per (batch, head), f16 weights ---------
// 1024 threads, thread (j=tid&255, kq=tid>>8) owns gate cols 4j..4j+3 for
// k-slice [64kq,64kq+64): 24 pairs/col in VGPRs + 8 in LDS. Single barrier
// per step: partials go to double-buffered packed-f16 LDS; every wave
// redundantly computes the epilogue for the 64 units of its own k-slice
// (lane<->unit), keeps c-state redundantly, and writes h pairs to a
// PRIVATE per-wave hp slice (own-wave read next step -> no 2nd barrier).
// xp gate values are prefetched scalars consumed only in the epilogue.
struct RArgs { const float* xp[3]; const unsigned* wt[3]; unsigned* outh[3]; };
__global__ __launch_bounds__(1024,1) void rec_kernel(RArgs a){
  extern __shared__ float lds[];
  unsigned* lw    = (unsigned*)lds;            // 32768 dwords (128 KB) weights
  unsigned* part2 = (unsigned*)(lds + 32768);  // 2 x 2048 dwords (16 KB) f16 partials
  unsigned* hp    = (unsigned*)(lds + 36864);  // 16 waves x 32 dwords (2 KB)
  int b = blockIdx.x, hd = blockIdx.y, tid = threadIdx.x;
  int j = tid & 255, kq = tid >> 8;
  int wave = tid >> 6, lane = tid & 63;
  int u = (kq << 6) + lane;                    // unit this lane epilogues
  const float* xp = a.xp[hd] + (size_t)b*Tn*G4;
  const unsigned* wt = a.wt[hd];
  unsigned* outh = a.outh[hd] + (size_t)b*Tn*128;
  bool storer = ((wave>>2) == (wave&3));       // waves 0,5,10,15: distinct SIMDs+groups
  unsigned* myhp = hp + wave*32;

  unsigned w[96];
  #pragma unroll
  for (int c=0;c<4;c++){
    #pragma unroll
    for (int i=0;i<6;i++){
      uint4 v = *(const uint4*)(wt + ((c*8+i)*1024 + tid)*4);
      w[(c*6+i)*4+0]=v.x; w[(c*6+i)*4+1]=v.y; w[(c*6+i)*4+2]=v.z; w[(c*6+i)*4+3]=v.w;
    }
    #pragma unroll
    for (int i=6;i<8;i++){
      uint4 v = *(const uint4*)(wt + ((c*8+i)*1024 + tid)*4);
      *(uint4*)(lw + ((c*2+(i-6))*1024 + tid)*4) = v;
    }
  }
  float cst = 0.0f;
  if (lane < 32) myhp[lane] = 0u;
  __syncthreads();

  for (int t=0; t<Tn; t++){
    // prefetch xp gates (coalesced; consumed post-barrier -> latency hidden)
    float xi = xp[t*G4 + u];
    float xf = xp[t*G4 + 256 + u];
    float xg = xp[t*G4 + 512 + u];
    float xo = xp[t*G4 + 768 + u];
    float ac0=0.f, ac1=0.f, ac2=0.f, ac3=0.f;
    #pragma unroll
    for (int ic=0; ic<6; ic++){
      uint4 hv = *(const uint4*)(myhp + 4*ic);
      ac0=fdot2_(w[0*24+ic*4+0],hv.x,ac0); ac0=fdot2_(w[0*24+ic*4+1],hv.y,ac0);
      ac0=fdot2_(w[0*24+ic*4+2],hv.z,ac0); ac0=fdot2_(w[0*24+ic*4+3],hv.w,ac0);
      ac1=fdot2_(w[1*24+ic*4+0],hv.x,ac1); ac1=fdot2_(w[1*24+ic*4+1],hv.y,ac1);
      ac1=fdot2_(w[1*24+ic*4+2],hv.z,ac1); ac1=fdot2_(w[1*24+ic*4+3],hv.w,ac1);
      ac2=fdot2_(w[2*24+ic*4+0],hv.x,ac2); ac2=fdot2_(w[2*24+ic*4+1],hv.y,ac2);
      ac2=fdot2_(w[2*24+ic*4+2],hv.z,ac2); ac2=fdot2_(w[2*24+ic*4+3],hv.w,ac2);
      ac3=fdot2_(w[3*24+ic*4+0],hv.x,ac3); ac3=fdot2_(w[3*24+ic*4+1],hv.y,ac3);
      ac3=fdot2_(w[3*24+ic*4+2],hv.z,ac3); ac3=fdot2_(w[3*24+ic*4+3],hv.w,ac3);
    }
    #pragma unroll
    for (int ic=6; ic<8; ic++){
      uint4 hv = *(const uint4*)(myhp + 4*ic);
      { uint4 lv = *(const uint4*)(lw + ((0*2+(ic-6))*1024 + tid)*4);
        ac0=fdot2_(lv.x,hv.x,ac0); ac0=fdot2_(lv.y,hv.y,ac0);
        ac0=fdot2_(lv.z,hv.z,ac0); ac0=fdot2_(lv.w,hv.w,ac0); }
      { uint4 lv = *(const uint4*)(lw + ((1*2+(ic-6))*1024 + tid)*4);
        ac1=fdot2_(lv.x,hv.x,ac1); ac1=fdot2_(lv.y,hv.y,ac1);
        ac1=fdot2_(lv.z,hv.z,ac1); ac1=fdot2_(lv.w,hv.w,ac1); }
      { uint4 lv = *(const uint4*)(lw + ((2*2+(ic-6))*1024 + tid)*4);
        ac2=fdot2_(lv.x,hv.x,ac2); ac2=fdot2_(lv.y,hv.y,ac2);
        ac2=fdot2_(lv.z,hv.z,ac2); ac2=fdot2_(lv.w,hv.w,ac2); }
      { uint4 lv = *(const uint4*)(lw + ((3*2+(ic-6))*1024 + tid)*4);
        ac3=fdot2_(lv.x,hv.x,ac3); ac3=fdot2_(lv.y,hv.y,ac3);
        ac3=fdot2_(lv.z,hv.z,ac3); ac3=fdot2_(lv.w,hv.w,ac3); }
    }
    unsigned* pb = part2 + (t&1)*2048;
    *(uint2*)(pb + kq*512 + 2*j) = make_uint2(packh_(ac0,ac1), packh_(ac2,ac3));
    __syncthreads();
    // epilogue: all waves, lane -> unit u of own k-slice (redundant x4/group)
    int pu = u >> 1, odd = u & 1;
    float gi = xi, gf = xf, gg = xg, go = xo;
    #pragma unroll
    for (int kqq=0; kqq<4; kqq++){
      gi += unpk_(pb[kqq*512 +       pu], odd);
      gf += unpk_(pb[kqq*512 + 128 + pu], odd);
      gg += unpk_(pb[kqq*512 + 256 + pu], odd);
      go += unpk_(pb[kqq*512 + 384 + pu], odd);
    }
    cst = sigmoidf_(gf)*cst + sigmoidf_(gi)*tanhf_(gg);
    float h = sigmoidf_(go)*tanhf_(cst);
    float hq = __shfl_xor(h, 1);
    if (!(lane & 1)){
      unsigned hh = packh_(h, hq);
      myhp[lane>>1] = hh;
      if (storer) outh[t*128 + (u>>1)] = hh;
    }
    // no 2nd barrier: part double-buffered; myhp is own-wave only
  }
}

// ---- per-feature mean/var stats over (B,T), packed f16 input -----------
struct SArgs { const unsigned* in[3]; float* stats[3]; };
__global__ void stats_kernel(SArgs a){
  int hd = blockIdx.y; int tid = threadIdx.x;
  const unsigned* in = a.in[hd] + (size_t)blockIdx.x*256*128;
  int pu = tid >> 1, odd = tid & 1;
  float s=0.f,q=0.f;
  for (int r=0;r<256;r++){ float v = unpk_(in[r*128 + pu], odd); s+=v; q+=v*v; }
  atomicAdd(&a.stats[hd][tid], s);
  atomicAdd(&a.stats[hd][Hdim+tid], q);
}

// ---- normalize shared output (packed f16 -> packed f16) ----------------
__global__ void norm_kernel(const unsigned* __restrict__ in, const float* __restrict__ stats,
   const float* __restrict__ g, const float* __restrict__ bta, unsigned* __restrict__ outh){
  int i2 = blockIdx.x*256 + threadIdx.x;   // BT*128 total
  int h2i = i2 & 127;
  int h0 = 2*h2i;
  h2t p = __builtin_bit_cast(h2t, in[i2]);
  float m0 = stats[h0]*(1.0f/BT),   v0 = stats[Hdim+h0]*(1.0f/BT) - m0*m0;
  float m1 = stats[h0+1]*(1.0f/BT), v1 = stats[Hdim+h0+1]*(1.0f/BT) - m1*m1;
  float lo = ((float)p.x-m0)*g[h0]*rsqrtf(v0+EPSc) + bta[h0];
  float hi = ((float)p.y-m1)*g[h0+1]*rsqrtf(v1+EPSc) + bta[h0+1];
  outh[i2] = packh_(lo, hi);
}

// ---- final: normalize last step of heads, fc + softmax -----------------
__global__ __launch_bounds__(256) void final_kernel(
  const unsigned* __restrict__ h0, const unsigned* __restrict__ h1, const unsigned* __restrict__ h2,
  const float* __restrict__ stats,    // base ws+S_BN; head hd at (1+hd)*512
  const float* __restrict__ hbg, const float* __restrict__ hbb,
  const float* __restrict__ actW, const float* __restrict__ actB,
  const float* __restrict__ tW, const float* __restrict__ tB,
  const float* __restrict__ rW, const float* __restrict__ rB,
  float* __restrict__ outp){
  __shared__ float v0[Bn*Hdim];
  __shared__ float lg[Bn*Cdim];
  int tid = threadIdx.x;
  for (int i=tid; i<Bn*Hdim; i+=256){
    int b=i>>8, h=i&255;
    float sm = stats[512 + h], sq = stats[512+256+h];
    float mean = sm*(1.0f/BT); float var = sq*(1.0f/BT) - mean*mean;
    float hv = unpk_(h0[(size_t)(b*Tn+63)*128 + (h>>1)], h&1);
    v0[i] = (hv - mean)*hbg[h]*rsqrtf(var+EPSc) + hbb[h];
  }
  __syncthreads();
  for (int i=tid; i<Bn*Cdim; i+=256){
    int b=i>>5, cc=i&31;
    float acc = actB[cc];
    const float* wrow = actW + cc*Hdim;
    const float* vrow = v0 + b*Hdim;
    #pragma unroll 4
    for (int h=0;h<Hdim;h++) acc = fmaf(vrow[h], wrow[h], acc);
    lg[i] = acc;
  }
  __syncthreads();
  if (tid < Bn){
    int b = tid;
    float m = -1e30f;
    #pragma unroll
    for (int cc=0; cc<Cdim; cc++) m = fmaxf(m, lg[b*Cdim+cc]);
    float e[Cdim]; float s = 0.f;
    #pragma unroll
    for (int cc=0; cc<Cdim; cc++){ float ee = __expf(lg[b*Cdim+cc]-m); e[cc]=ee; s+=ee; }
    float inv = 1.0f/s;
    #pragma unroll
    for (int cc=0; cc<Cdim; cc++) outp[b*Cdim+cc] = e[cc]*inv;
  }
  if (tid < 64){
    int b = tid & 31; int w = tid >> 5;
    const unsigned* hh = w ? h2 : h1;
    const float* fw = w ? rW : tW;
    float fb = w ? rB[0] : tB[0];
    int hd = 1 + w;
    float acc = fb;
    for (int h=0; h<Hdim; h++){
      float sm = stats[(1+hd)*512 + h], sq = stats[(1+hd)*512+256+h];
      float mean = sm*(1.0f/BT); float var = sq*(1.0f/BT) - mean*mean;
      float hv = unpk_(hh[(size_t)(b*Tn+63)*128 + (h>>1)], h&1);
      float v = (hv - mean)*hbg[hd*Hdim+h]*rsqrtf(var+EPSc) + hbb[hd*Hdim+h];
      acc = fmaf(v, fw[h], acc);
    }
    outp[1024 + w*32 + b] = acc;
  }
}

extern "C" void kernel_launch(void* const* d_in, const int* in_sizes, int n_in,
                              void* d_out, int out_size, void* d_ws, size_t ws_size,
                              hipStream_t stream){
  const float* data_feats = (const float*)d_in[0];
  const float* gat   = (const float*)d_in[1];
  const int*   row_ids  = (const int*)d_in[2];
  const int*   node_ids = (const int*)d_in[3];
  const float* sWih0 = (const float*)d_in[4];
  const float* sWhh0 = (const float*)d_in[5];
  const float* sb0   = (const float*)d_in[6];
  const float* sWih1 = (const float*)d_in[7];
  const float* sWhh1 = (const float*)d_in[8];
  const float* sb1   = (const float*)d_in[9];
  const float* hWih  = (const float*)d_in[10];
  const float* hWhh  = (const float*)d_in[11];
  const float* hb    = (const float*)d_in[12];
  const float* bng   = (const float*)d_in[13];
  const float* bnb   = (const float*)d_in[14];
  const float* bsg   = (const float*)d_in[15];
  const float* bsb   = (const float*)d_in[16];
  const float* hbg   = (const float*)d_in[17];
  const float* hbb   = (const float*)d_in[18];
  const float* actW  = (const float*)d_in[19];
  const float* actB  = (const float*)d_in[20];
  const float* tW    = (const float*)d_in[21];
  const float* tB    = (const float*)d_in[22];
  const float* rW    = (const float*)d_in[23];
  const float* rB    = (const float*)d_in[24];
  float* ws  = (float*)d_ws;
  float* out = (float*)d_out;

  // workspace layout (float offsets)
  const size_t S_GAT = 0;                         // 64
  const size_t S_BN  = 64;                        // 4*512
  const size_t TABLE = 2112;                      // 40000 ints
  const size_t WIHP  = 42112;                     // 8 x 131072 uints (Wih^T f16)
  const size_t PSLOT = 131072;
  const size_t WHHP  = WIHP + 8*PSLOT;            // 8 x 131072 uints (Whh f16)
  const size_t LSTM_INH = WHHP + 8*PSLOT;         // BT*32 uints
  const size_t XPOFF = LSTM_INH + 65536;          // 3 x 2,097,152 fp32
  const size_t BUF0H = XPOFF + 3*2097152;         // BT*128 uints (shared L0 h)
  const size_t BUF1H = BUF0H + 262144;            // BT*128 uints (shared L1 h)
  const size_t BUFNH = BUF1H + 262144;            // BT*128 uints (normalized)
  const size_t HB0H  = BUFNH + 262144;            // 3 x BT*128 uints (heads L0 h)
  const size_t HB1H  = HB0H + 3*262144;           // 3 x BT*128 uints (heads L1 h)

  const int REC_LDS = 149504;                     // 128K w + 16K part2 + 2K hp
  hipFuncSetAttribute((const void*)rec_kernel, hipFuncAttributeMaxDynamicSharedMemorySize, REC_LDS);

  init_kernel<<<157,256,0,stream>>>(ws);
  bn_stats_kernel2<<<1024,256,0,stream>>>(gat, ws+S_GAT);
  table_kernel<<<(Ndim+255)/256,256,0,stream>>>(node_ids, (int*)(ws+TABLE));
  build_input_kernel<<<256,256,0,stream>>>(data_feats, gat, row_ids, (int*)(ws+TABLE),
                                           ws+S_GAT, bng, bnb, (unsigned*)(ws+LSTM_INH));

  // Wih pack+transpose to f16 [k2][1024]
  unsigned* wih = (unsigned*)(ws + WIHP);
  TArgs ta;
  ta.src[0]=sWih0; ta.K[0]=64;
  ta.src[1]=sWih1; ta.K[1]=256;
  for (int hd=0; hd<3; hd++) for (int l=0;l<2;l++){
    ta.src[2+hd*2+l] = hWih + (size_t)(hd*2+l)*G4*Hdim; ta.K[2+hd*2+l] = 256;
  }
  for (int i=0;i<8;i++) ta.dst[i] = wih + (size_t)i*PSLOT;
  packwih_kernel<<<dim3(128,8),dim3(32,8),0,stream>>>(ta);

  // Whh f16 pack (for rec)
  unsigned* whh = (unsigned*)(ws + WHHP);
  PkArgs pka;
  pka.src[0]=sWhh0; pka.src[1]=sWhh1;
  for (int hd=0; hd<3; hd++) for (int l=0;l<2;l++)
    pka.src[2+hd*2+l] = hWhh + (size_t)(hd*2+l)*G4*Hdim;
  pack_kernel<<<4096,256,0,stream>>>(pka, whh);

  PArgs pa; RArgs ra; SArgs sa;
  // shared layer 0
  pa.K2=32; pa.x[0]=(unsigned*)(ws+LSTM_INH); pa.wt[0]=wih+0*PSLOT; pa.bias[0]=sb0; pa.out[0]=ws+XPOFF;
  proj_kernel<<<dim3(256,4,1),256,0,stream>>>(pa);
  ra.xp[0]=ws+XPOFF; ra.wt[0]=whh+0*PSLOT; ra.outh[0]=(unsigned*)(ws+BUF0H);
  rec_kernel<<<dim3(32,1),1024,REC_LDS,stream>>>(ra);
  // shared layer 1
  pa.K2=128; pa.x[0]=(unsigned*)(ws+BUF0H); pa.wt[0]=wih+1*PSLOT; pa.bias[0]=sb1; pa.out[0]=ws+XPOFF;
  proj_kernel<<<dim3(256,4,1),256,0,stream>>>(pa);
  ra.xp[0]=ws+XPOFF; ra.wt[0]=whh+1*PSLOT; ra.outh[0]=(unsigned*)(ws+BUF1H);
  rec_kernel<<<dim3(32,1),1024,REC_LDS,stream>>>(ra);
  // shared batchnorm
  sa.in[0]=(unsigned*)(ws+BUF1H); sa.stats[0]=ws+S_BN;
  stats_kernel<<<dim3(8,1),256,0,stream>>>(sa);
  norm_kernel<<<1024,256,0,stream>>>((unsigned*)(ws+BUF1H), ws+S_BN, bsg, bsb, (unsigned*)(ws+BUFNH));
  // heads layer 0
  pa.K2=128;
  for (int hd=0;hd<3;hd++){
    pa.x[hd]=(unsigned*)(ws+BUFNH); pa.wt[hd]=wih+(size_t)(2+hd*2)*PSLOT; pa.bias[hd]=hb + (size_t)(hd*2)*G4;
    pa.out[hd]=ws+XPOFF+(size_t)hd*2097152;
  }
  proj_kernel<<<dim3(256,4,3),256,0,stream>>>(pa);
  for (int hd=0;hd<3;hd++){
    ra.xp[hd]=ws+XPOFF+(size_t)hd*2097152; ra.wt[hd]=whh+(size_t)(2+hd*2)*PSLOT;
    ra.outh[hd]=(unsigned*)(ws+HB0H)+(size_t)hd*262144;
  }
  rec_kernel<<<dim3(32,3),1024,REC_LDS,stream>>>(ra);
  // heads layer 1
  for (int hd=0;hd<3;hd++){
    pa.x[hd]=(unsigned*)(ws+HB0H)+(size_t)hd*262144; pa.wt[hd]=wih+(size_t)(2+hd*2+1)*PSLOT;
    pa.bias[hd]=hb + (size_t)(hd*2+1)*G4;
    pa.out[hd]=ws+XPOFF+(size_t)hd*2097152;
  }
  proj_kernel<<<dim3(256,4,3),256,0,stream>>>(pa);
  for (int hd=0;hd<3;hd++){
    ra.xp[hd]=ws+XPOFF+(size_t)hd*2097152; ra.wt[hd]=whh+(size_t)(2+hd*2+1)*PSLOT;
    ra.outh[hd]=(unsigned*)(ws+HB1H)+(size_t)hd*262144;
  }
  rec_kernel<<<dim3(32,3),1024,REC_LDS,stream>>>(ra);
  // heads batchnorm stats
  for (int hd=0;hd<3;hd++){ sa.in[hd]=(unsigned*)(ws+HB1H)+(size_t)hd*262144; sa.stats[hd]=ws+S_BN+(size_t)(1+hd)*512; }
  stats_kernel<<<dim3(8,3),256,0,stream>>>(sa);
  // final outputs
  final_kernel<<<1,256,0,stream>>>((unsigned*)(ws+HB1H), (unsigned*)(ws+HB1H)+262144, (unsigned*)(ws+HB1H)+2*262144,
                                   ws+S_BN, hbg, hbb, actW, actB, tW, tB, rW, rB, out);
}

// Round 6
// 949.137 us; speedup vs baseline: 1.2684x; 1.2684x over previous
//
#include <hip/hip_runtime.h>
#include <hip/hip_fp16.h>
#include <math.h>

#define Bn 32
#define Tn 64
#define Fdim 32
#define Gdim 32
#define Hdim 256
#define Ndim 20000
#define Cdim 32
#define G4 1024      // 4*H
#define BT 2048      // B*T
#define EPSc 1e-5f

__device__ __forceinline__ float sigmoidf_(float x){ return 1.0f/(1.0f + __expf(-x)); }
__device__ __forceinline__ float tanhf_(float x){ return 2.0f/(1.0f+__expf(-2.0f*x)) - 1.0f; }

typedef _Float16 h2t __attribute__((ext_vector_type(2)));

__device__ __forceinline__ float fdot2_(unsigned w, unsigned h, float acc){
#if defined(__has_builtin) && __has_builtin(__builtin_amdgcn_fdot2)
  return __builtin_amdgcn_fdot2(__builtin_bit_cast(h2t, w), __builtin_bit_cast(h2t, h), acc, false);
#else
  h2t a = __builtin_bit_cast(h2t, w), b = __builtin_bit_cast(h2t, h);
  acc = fmaf((float)a.x, (float)b.x, acc);
  return fmaf((float)a.y, (float)b.y, acc);
#endif
}

__device__ __forceinline__ unsigned packh_(float lo, float hi){
  unsigned ulo = (unsigned)__half_as_ushort(__float2half(lo));
  unsigned uhi = (unsigned)__half_as_ushort(__float2half(hi));
  return ulo | (uhi << 16);
}

__device__ __forceinline__ float unpk_(unsigned d, int odd){
  h2t p = __builtin_bit_cast(h2t, d);
  return odd ? (float)p.y : (float)p.x;
}

// ---- init workspace stats + lookup table -------------------------------
__global__ void init_kernel(float* ws){
  int i = blockIdx.x*256 + threadIdx.x;
  if (i < 2112) ws[i] = 0.0f;                  // gat stats (64) + bn stats (4*512)
  int* table = (int*)(ws + 2112);
  if (i < 40000) table[i] = 0x7fffffff;
}

// ---- gat_output per-channel mean/var reduction (float4 loads) ----------
__global__ void bn_stats_kernel2(const float* __restrict__ gat, float* __restrict__ sums){
  __shared__ float ss[256], sq[256];
  int tid = threadIdx.x;
  int idx = blockIdx.x*256 + tid;
  int stride = gridDim.x*256;
  const int total4 = Bn*Ndim*Gdim/4;
  const float4* g4 = (const float4*)gat;
  float4 s = make_float4(0.f,0.f,0.f,0.f), q = make_float4(0.f,0.f,0.f,0.f);
  for (int i=idx; i<total4; i+=stride){
    float4 v = g4[i];
    s.x+=v.x; s.y+=v.y; s.z+=v.z; s.w+=v.w;
    q.x+=v.x*v.x; q.y+=v.y*v.y; q.z+=v.z*v.z; q.w+=v.w*v.w;
  }
  // threads with equal (tid&7) cover the same 4 channels (g0=4*(tid&7))
  ss[tid]=s.x; sq[tid]=q.x; __syncthreads();
  for (int off=128; off>=8; off>>=1){ if(tid<off){ ss[tid]+=ss[tid+off]; sq[tid]+=sq[tid+off]; } __syncthreads(); }
  if (tid<8){ atomicAdd(&sums[4*tid+0], ss[tid]); atomicAdd(&sums[32+4*tid+0], sq[tid]); }
  __syncthreads();
  ss[tid]=s.y; sq[tid]=q.y; __syncthreads();
  for (int off=128; off>=8; off>>=1){ if(tid<off){ ss[tid]+=ss[tid+off]; sq[tid]+=sq[tid+off]; } __syncthreads(); }
  if (tid<8){ atomicAdd(&sums[4*tid+1], ss[tid]); atomicAdd(&sums[32+4*tid+1], sq[tid]); }
  __syncthreads();
  ss[tid]=s.z; sq[tid]=q.z; __syncthreads();
  for (int off=128; off>=8; off>>=1){ if(tid<off){ ss[tid]+=ss[tid+off]; sq[tid]+=sq[tid+off]; } __syncthreads(); }
  if (tid<8){ atomicAdd(&sums[4*tid+2], ss[tid]); atomicAdd(&sums[32+4*tid+2], sq[tid]); }
  __syncthreads();
  ss[tid]=s.w; sq[tid]=q.w; __syncthreads();
  for (int off=128; off>=8; off>>=1){ if(tid<off){ ss[tid]+=ss[tid+off]; sq[tid]+=sq[tid+off]; } __syncthreads(); }
  if (tid<8){ atomicAdd(&sums[4*tid+3], ss[tid]); atomicAdd(&sums[32+4*tid+3], sq[tid]); }
}

// ---- node id -> first index table --------------------------------------
__global__ void table_kernel(const int* __restrict__ node_ids, int* __restrict__ table){
  int i = blockIdx.x*256 + threadIdx.x;
  if (i < Ndim) atomicMin(&table[node_ids[i]], i);
}

// ---- gather + normalize + concat -> lstm_in packed f16 (BT,32 pairs) ---
__global__ void build_input_kernel(const float* __restrict__ feats, const float* __restrict__ gat,
    const int* __restrict__ row_ids, const int* __restrict__ table, const float* __restrict__ sums,
    const float* __restrict__ bng, const float* __restrict__ bnb, unsigned* __restrict__ out){
  int gt = blockIdx.x*256 + threadIdx.x;     // BT*32 total
  int pos = gt >> 5; int k2 = gt & 31;
  float lo, hi;
  if (k2 < 16){
    float2 v = *(const float2*)(feats + pos*Fdim + 2*k2);
    lo = v.x; hi = v.y;
  } else {
    int g0 = 2*(k2-16);
    int r = row_ids[pos];
    int idx = table[r];
    if (idx < Ndim){
      int b = pos / Tn;
      float2 x = *(const float2*)(gat + (size_t)(b*Ndim + idx)*Gdim + g0);
      const float cnt = (float)(Bn*Ndim);
      float m0 = sums[g0]/cnt,   v0 = sums[32+g0]/cnt - m0*m0;
      float m1 = sums[g0+1]/cnt, v1 = sums[32+g0+1]/cnt - m1*m1;
      lo = (x.x-m0)*bng[g0]*rsqrtf(v0+EPSc) + bnb[g0];
      hi = (x.y-m1)*bng[g0+1]*rsqrtf(v1+EPSc) + bnb[g0+1];
    } else { lo = 0.0f; hi = 0.0f; }
  }
  out[gt] = packh_(lo, hi);
}

// ---- pack+transpose Wih (1024,K) fp32 -> (K/2,1024) f16 pairs ----------
struct TArgs { const float* src[8]; unsigned* dst[8]; int K[8]; };
__global__ void packwih_kernel(TArgs a){
  __shared__ unsigned tile[32][33];
  int mat = blockIdx.y;
  int K = a.K[mat];
  int K2 = K >> 1;
  int ktiles = K2 >> 5;                  // 1 (K=64) or 4 (K=256)
  int tk = blockIdx.x & 3;               // k2-tile
  int tn = blockIdx.x >> 2;              // n-tile 0..31
  if (tk >= ktiles) return;
  const float* src = a.src[mat];
  unsigned* dst = a.dst[mat];
  int tx = threadIdx.x, ty = threadIdx.y;   // 32 x 8
  int n0 = tn*32, k2_0 = tk*32;
  #pragma unroll
  for (int i=0;i<4;i++){
    int nn = ty + 8*i;
    const float* p = src + (size_t)(n0+nn)*K + 2*(k2_0 + tx);
    tile[nn][tx] = packh_(p[0], p[1]);
  }
  __syncthreads();
  #pragma unroll
  for (int i=0;i<4;i++){
    int r = ty + 8*i;  // local k2
    dst[(size_t)(k2_0 + r)*G4 + n0 + tx] = tile[tx][r];
  }
}

// ---- pack Whh (1024,256) fp32 -> f16 pairs, rec v3 layout --------------
// Per matrix 131072 dwords. Thread tid=(j=tid&255,kq=tid>>8) of the
// 512-thread rec owns cols c*256+j over k in [128kq,128kq+128) (pairs
// pp=0..63). Resident part (pp<52): dword idx = ((c*13+g)*512+tid)*4+e,
// pp=4g+e. LDS part (pp>=52): 106496 + ((c*3+g)*512+tid)*4+e, pp=52+4g+e.
struct PkArgs { const float* src[8]; };
__global__ void pack_kernel(PkArgs a, unsigned* __restrict__ dst){
  int gid = blockIdx.x*256 + threadIdx.x;   // 8*131072 total
  int m = gid >> 17;
  int rem = gid & 0x1FFFF;
  int e, tidv, g, c, pp;
  if (rem < 106496){
    e = rem & 3; int t4 = rem >> 2; tidv = t4 & 511; int gg = t4 >> 9;
    g = gg % 13; c = gg / 13; pp = g*4 + e;
  } else {
    int q = rem - 106496;
    e = q & 3; int t4 = q >> 2; tidv = t4 & 511; int gg = t4 >> 9;
    g = gg % 3; c = gg / 3; pp = 52 + g*4 + e;
  }
  int col = c*256 + (tidv & 255);
  int kq = tidv >> 8;
  int k = kq*128 + 2*pp;
  const float* W = a.src[m];
  dst[gid] = packh_(W[col*256 + k], W[col*256 + k + 1]);
}

// ---- input projection: out(m,1024) = x(m,K) @ WT(K,1024) + bias --------
struct PArgs { const unsigned* x[3]; const unsigned* wt[3]; const float* bias[3]; float* out[3]; int K2; };
__global__ __launch_bounds__(256) void proj_kernel(PArgs a){
  int hd = blockIdx.z;
  int n  = blockIdx.y*256 + threadIdx.x;
  int m0 = blockIdx.x*8;
  int K2 = a.K2;
  const unsigned* xh = a.x[hd] + (size_t)m0*K2;
  const unsigned* wt = a.wt[hd];
  float bv = a.bias[hd][n];
  float acc[8];
  #pragma unroll
  for (int i=0;i<8;i++) acc[i]=bv;
  for (int k2=0;k2<K2;k2+=4){
    unsigned w0 = wt[(size_t)(k2+0)*G4+n];
    unsigned w1 = wt[(size_t)(k2+1)*G4+n];
    unsigned w2 = wt[(size_t)(k2+2)*G4+n];
    unsigned w3 = wt[(size_t)(k2+3)*G4+n];
    #pragma unroll
    for (int i=0;i<8;i++){
      uint4 xv = *(const uint4*)(xh + i*K2 + k2);   // uniform -> s_load_dwordx4
      acc[i]=fdot2_(w0,xv.x,acc[i]); acc[i]=fdot2_(w1,xv.y,acc[i]);
      acc[i]=fdot2_(w2,xv.z,acc[i]); acc[i]=fdot2_(w3,xv.w,acc[i]);
    }
  }
  float* out = a.out[hd] + (size_t)m0*G4 + n;
  #pragma unroll
  for (int i=0;i<8;i++) out[i*G4]=acc[i];
}

// ---- LSTM recurrence v3: 512 threads, 2 waves/SIMD, 256-VGPR cap -------
// Thread (j=tid&255, kq=tid>>8) owns cols {j,256+j,512+j,768+j} over the
// k half-slice [128kq,128kq+128): 52 pairs/col resident in VGPRs (w4[52]),
// 12 pairs/col streamed from LDS (96 KB, interleaved with the dots so the
// LDS pipe overlaps VALU via 2-wave/SIMD alternation). h pairs in shared
// double-buffered hp (wave-uniform kq -> broadcast reads). Partials:
// packed-f16 uint2, 2-way reduce. Epilogue on waves 0-3 (one/SIMD) with
// xp prefetched at step top; outh stored AFTER barrier 2 (retires during
// next dot phase -> no drain at a barrier).
struct RArgs { const float* xp[3]; const unsigned* wt[3]; unsigned* outh[3]; };
__global__ __launch_bounds__(512,2) void rec_kernel(RArgs a){
  extern __shared__ unsigned sl[];
  unsigned* lw   = sl;            // 24576 dwords (96 KB) streamed weights
  unsigned* part = sl + 24576;    // 1024 dwords (4 KB)  f16 partials
  unsigned* hp   = sl + 25600;    // 2 x 128 dwords (1 KB)
  int b = blockIdx.x, hd = blockIdx.y, tid = threadIdx.x;
  int kq = tid >> 8;
  const float* xp = a.xp[hd] + (size_t)b*Tn*G4;
  const unsigned* wt = a.wt[hd];
  unsigned* outh = a.outh[hd] + (size_t)b*Tn*128;
  bool epi = (tid < 256);
  int u = tid;                                  // epilogue unit (epi only)

  uint4 w4[52];
  #pragma unroll
  for (int c=0;c<4;c++)
    #pragma unroll
    for (int g=0; g<13; g++)
      w4[c*13+g] = *(const uint4*)(wt + ((size_t)(c*13+g)*512 + tid)*4);
  #pragma unroll
  for (int c=0;c<4;c++)
    #pragma unroll
    for (int g=0; g<3; g++){
      uint4 v = *(const uint4*)(wt + 106496 + ((size_t)(c*3+g)*512 + tid)*4);
      *(uint4*)(lw + ((c*3+g)*512 + tid)*4) = v;
    }
  if (tid < 128) hp[tid] = 0u;
  float cst = 0.f;
  __syncthreads();

  int p = 0;
  for (int t=0; t<Tn; t++){
    float xi,xf,xg,xo;
    if (epi){
      xi = xp[t*G4 + u]; xf = xp[t*G4+256+u]; xg = xp[t*G4+512+u]; xo = xp[t*G4+768+u];
    }
    const unsigned* hrow = hp + p*128 + kq*64;
    float ac0=0.f, ac1=0.f, ac2=0.f, ac3=0.f;
    #pragma unroll
    for (int g=0; g<13; g++){
      uint4 hv = *(const uint4*)(hrow + 4*g);
      uint4 a0 = w4[g], a1 = w4[13+g], a2 = w4[26+g], a3 = w4[39+g];
      ac0=fdot2_(a0.x,hv.x,ac0); ac1=fdot2_(a1.x,hv.x,ac1); ac2=fdot2_(a2.x,hv.x,ac2); ac3=fdot2_(a3.x,hv.x,ac3);
      ac0=fdot2_(a0.y,hv.y,ac0); ac1=fdot2_(a1.y,hv.y,ac1); ac2=fdot2_(a2.y,hv.y,ac2); ac3=fdot2_(a3.y,hv.y,ac3);
      ac0=fdot2_(a0.z,hv.z,ac0); ac1=fdot2_(a1.z,hv.z,ac1); ac2=fdot2_(a2.z,hv.z,ac2); ac3=fdot2_(a3.z,hv.z,ac3);
      ac0=fdot2_(a0.w,hv.w,ac0); ac1=fdot2_(a1.w,hv.w,ac1); ac2=fdot2_(a2.w,hv.w,ac2); ac3=fdot2_(a3.w,hv.w,ac3);
    }
    #pragma unroll
    for (int g=0; g<3; g++){
      uint4 hv = *(const uint4*)(hrow + 4*(13+g));
      uint4 l0 = *(const uint4*)(lw + ((0*3+g)*512 + tid)*4);
      uint4 l1 = *(const uint4*)(lw + ((1*3+g)*512 + tid)*4);
      uint4 l2 = *(const uint4*)(lw + ((2*3+g)*512 + tid)*4);
      uint4 l3 = *(const uint4*)(lw + ((3*3+g)*512 + tid)*4);
      ac0=fdot2_(l0.x,hv.x,ac0); ac1=fdot2_(l1.x,hv.x,ac1); ac2=fdot2_(l2.x,hv.x,ac2); ac3=fdot2_(l3.x,hv.x,ac3);
      ac0=fdot2_(l0.y,hv.y,ac0); ac1=fdot2_(l1.y,hv.y,ac1); ac2=fdot2_(l2.y,hv.y,ac2); ac3=fdot2_(l3.y,hv.y,ac3);
      ac0=fdot2_(l0.z,hv.z,ac0); ac1=fdot2_(l1.z,hv.z,ac1); ac2=fdot2_(l2.z,hv.z,ac2); ac3=fdot2_(l3.z,hv.z,ac3);
      ac0=fdot2_(l0.w,hv.w,ac0); ac1=fdot2_(l1.w,hv.w,ac1); ac2=fdot2_(l2.w,hv.w,ac2); ac3=fdot2_(l3.w,hv.w,ac3);
    }
    int j = tid & 255;
    *(uint2*)(part + kq*512 + 2*j) = make_uint2(packh_(ac0,ac1), packh_(ac2,ac3));
    __syncthreads();
    unsigned hh = 0u;
    if (epi){
      unsigned p0a = part[2*u], p0b = part[2*u+1];
      unsigned p1a = part[512+2*u], p1b = part[512+2*u+1];
      float gi = xi + unpk_(p0a,0) + unpk_(p1a,0);
      float gf = xf + unpk_(p0a,1) + unpk_(p1a,1);
      float gg = xg + unpk_(p0b,0) + unpk_(p1b,0);
      float go = xo + unpk_(p0b,1) + unpk_(p1b,1);
      cst = sigmoidf_(gf)*cst + sigmoidf_(gi)*tanhf_(gg);
      float h = sigmoidf_(go)*tanhf_(cst);
      float hq = __shfl_xor(h, 1);
      if (!(u & 1)){
        hh = packh_(h, hq);
        hp[(p^1)*128 + (u>>1)] = hh;
      }
    }
    __syncthreads();
    // store after the barrier: retires during next dot phase, no drain cost
    if (epi && !(u & 1)) outh[t*128 + (u>>1)] = hh;
    p ^= 1;
  }
}

// ---- per-feature mean/var stats over (B,T), packed f16 input -----------
struct SArgs { const unsigned* in[3]; float* stats[3]; };
__global__ void stats_kernel(SArgs a){
  int hd = blockIdx.y; int tid = threadIdx.x;
  const unsigned* in = a.in[hd] + (size_t)blockIdx.x*256*128;
  int pu = tid >> 1, odd = tid & 1;
  float s=0.f,q=0.f;
  for (int r=0;r<256;r++){ float v = unpk_(in[r*128 + pu], odd); s+=v; q+=v*v; }
  atomicAdd(&a.stats[hd][tid], s);
  atomicAdd(&a.stats[hd][Hdim+tid], q);
}

// ---- normalize shared output (packed f16 -> packed f16) ----------------
__global__ void norm_kernel(const unsigned* __restrict__ in, const float* __restrict__ stats,
   const float* __restrict__ g, const float* __restrict__ bta, unsigned* __restrict__ outh){
  int i2 = blockIdx.x*256 + threadIdx.x;   // BT*128 total
  int h2i = i2 & 127;
  int h0 = 2*h2i;
  h2t p = __builtin_bit_cast(h2t, in[i2]);
  float m0 = stats[h0]*(1.0f/BT),   v0 = stats[Hdim+h0]*(1.0f/BT) - m0*m0;
  float m1 = stats[h0+1]*(1.0f/BT), v1 = stats[Hdim+h0+1]*(1.0f/BT) - m1*m1;
  float lo = ((float)p.x-m0)*g[h0]*rsqrtf(v0+EPSc) + bta[h0];
  float hi = ((float)p.y-m1)*g[h0+1]*rsqrtf(v1+EPSc) + bta[h0+1];
  outh[i2] = packh_(lo, hi);
}

// ---- final: normalize last step of heads, fc + softmax -----------------
__global__ __launch_bounds__(256) void final_kernel(
  const unsigned* __restrict__ h0, const unsigned* __restrict__ h1, const unsigned* __restrict__ h2,
  const float* __restrict__ stats,    // base ws+S_BN; head hd at (1+hd)*512
  const float* __restrict__ hbg, const float* __restrict__ hbb,
  const float* __restrict__ actW, const float* __restrict__ actB,
  const float* __restrict__ tW, const float* __restrict__ tB,
  const float* __restrict__ rW, const float* __restrict__ rB,
  float* __restrict__ outp){
  __shared__ float v0[Bn*Hdim];
  __shared__ float lg[Bn*Cdim];
  int tid = threadIdx.x;
  for (int i=tid; i<Bn*Hdim; i+=256){
    int b=i>>8, h=i&255;
    float sm = stats[512 + h], sq = stats[512+256+h];
    float mean = sm*(1.0f/BT); float var = sq*(1.0f/BT) - mean*mean;
    float hv = unpk_(h0[(size_t)(b*Tn+63)*128 + (h>>1)], h&1);
    v0[i] = (hv - mean)*hbg[h]*rsqrtf(var+EPSc) + hbb[h];
  }
  __syncthreads();
  for (int i=tid; i<Bn*Cdim; i+=256){
    int b=i>>5, cc=i&31;
    float acc = actB[cc];
    const float* wrow = actW + cc*Hdim;
    const float* vrow = v0 + b*Hdim;
    #pragma unroll 4
    for (int h=0;h<Hdim;h++) acc = fmaf(vrow[h], wrow[h], acc);
    lg[i] = acc;
  }
  __syncthreads();
  if (tid < Bn){
    int b = tid;
    float m = -1e30f;
    #pragma unroll
    for (int cc=0; cc<Cdim; cc++) m = fmaxf(m, lg[b*Cdim+cc]);
    float e[Cdim]; float s = 0.f;
    #pragma unroll
    for (int cc=0; cc<Cdim; cc++){ float ee = __expf(lg[b*Cdim+cc]-m); e[cc]=ee; s+=ee; }
    float inv = 1.0f/s;
    #pragma unroll
    for (int cc=0; cc<Cdim; cc++) outp[b*Cdim+cc] = e[cc]*inv;
  }
  if (tid < 64){
    int b = tid & 31; int w = tid >> 5;
    const unsigned* hh = w ? h2 : h1;
    const float* fw = w ? rW : tW;
    float fb = w ? rB[0] : tB[0];
    int hd = 1 + w;
    float acc = fb;
    for (int h=0; h<Hdim; h++){
      float sm = stats[(1+hd)*512 + h], sq = stats[(1+hd)*512+256+h];
      float mean = sm*(1.0f/BT); float var = sq*(1.0f/BT) - mean*mean;
      float hv = unpk_(hh[(size_t)(b*Tn+63)*128 + (h>>1)], h&1);
      float v = (hv - mean)*hbg[hd*Hdim+h]*rsqrtf(var+EPSc) + hbb[hd*Hdim+h];
      acc = fmaf(v, fw[h], acc);
    }
    outp[1024 + w*32 + b] = acc;
  }
}

extern "C" void kernel_launch(void* const* d_in, const int* in_sizes, int n_in,
                              void* d_out, int out_size, void* d_ws, size_t ws_size,
                              hipStream_t stream){
  const float* data_feats = (const float*)d_in[0];
  const float* gat   = (const float*)d_in[1];
  const int*   row_ids  = (const int*)d_in[2];
  const int*   node_ids = (const int*)d_in[3];
  const float* sWih0 = (const float*)d_in[4];
  const float* sWhh0 = (const float*)d_in[5];
  const float* sb0   = (const float*)d_in[6];
  const float* sWih1 = (const float*)d_in[7];
  const float* sWhh1 = (const float*)d_in[8];
  const float* sb1   = (const float*)d_in[9];
  const float* hWih  = (const float*)d_in[10];
  const float* hWhh  = (const float*)d_in[11];
  const float* hb    = (const float*)d_in[12];
  const float* bng   = (const float*)d_in[13];
  const float* bnb   = (const float*)d_in[14];
  const float* bsg   = (const float*)d_in[15];
  const float* bsb   = (const float*)d_in[16];
  const float* hbg   = (const float*)d_in[17];
  const float* hbb   = (const float*)d_in[18];
  const float* actW  = (const float*)d_in[19];
  const float* actB  = (const float*)d_in[20];
  const float* tW    = (const float*)d_in[21];
  const float* tB    = (const float*)d_in[22];
  const float* rW    = (const float*)d_in[23];
  const float* rB    = (const float*)d_in[24];
  float* ws  = (float*)d_ws;
  float* out = (float*)d_out;

  // workspace layout (float offsets)
  const size_t S_GAT = 0;                         // 64
  const size_t S_BN  = 64;                        // 4*512
  const size_t TABLE = 2112;                      // 40000 ints
  const size_t WIHP  = 42112;                     // 8 x 131072 uints (Wih^T f16)
  const size_t PSLOT = 131072;
  const size_t WHHP  = WIHP + 8*PSLOT;            // 8 x 131072 uints (Whh f16, rec layout)
  const size_t LSTM_INH = WHHP + 8*PSLOT;         // BT*32 uints
  const size_t XPOFF = LSTM_INH + 65536;          // 3 x 2,097,152 fp32
  const size_t BUF0H = XPOFF + 3*2097152;         // BT*128 uints (shared L0 h)
  const size_t BUF1H = BUF0H + 262144;            // BT*128 uints (shared L1 h)
  const size_t BUFNH = BUF1H + 262144;            // BT*128 uints (normalized)
  const size_t HB0H  = BUFNH + 262144;            // 3 x BT*128 uints (heads L0 h)
  const size_t HB1H  = HB0H + 3*262144;           // 3 x BT*128 uints (heads L1 h)

  const int REC_LDS = 103424;                     // 96K lw + 4K part + 1K hp
  hipFuncSetAttribute((const void*)rec_kernel, hipFuncAttributeMaxDynamicSharedMemorySize, REC_LDS);

  init_kernel<<<157,256,0,stream>>>(ws);
  bn_stats_kernel2<<<1024,256,0,stream>>>(gat, ws+S_GAT);
  table_kernel<<<(Ndim+255)/256,256,0,stream>>>(node_ids, (int*)(ws+TABLE));
  build_input_kernel<<<256,256,0,stream>>>(data_feats, gat, row_ids, (int*)(ws+TABLE),
                                           ws+S_GAT, bng, bnb, (unsigned*)(ws+LSTM_INH));

  // Wih pack+transpose to f16 [k2][1024]
  unsigned* wih = (unsigned*)(ws + WIHP);
  TArgs ta;
  ta.src[0]=sWih0; ta.K[0]=64;
  ta.src[1]=sWih1; ta.K[1]=256;
  for (int hd=0; hd<3; hd++) for (int l=0;l<2;l++){
    ta.src[2+hd*2+l] = hWih + (size_t)(hd*2+l)*G4*Hdim; ta.K[2+hd*2+l] = 256;
  }
  for (int i=0;i<8;i++) ta.dst[i] = wih + (size_t)i*PSLOT;
  packwih_kernel<<<dim3(128,8),dim3(32,8),0,stream>>>(ta);

  // Whh f16 pack (rec v3 layout)
  unsigned* whh = (unsigned*)(ws + WHHP);
  PkArgs pka;
  pka.src[0]=sWhh0; pka.src[1]=sWhh1;
  for (int hd=0; hd<3; hd++) for (int l=0;l<2;l++)
    pka.src[2+hd*2+l] = hWhh + (size_t)(hd*2+l)*G4*Hdim;
  pack_kernel<<<4096,256,0,stream>>>(pka, whh);

  PArgs pa; RArgs ra; SArgs sa;
  // shared layer 0
  pa.K2=32; pa.x[0]=(unsigned*)(ws+LSTM_INH); pa.wt[0]=wih+0*PSLOT; pa.bias[0]=sb0; pa.out[0]=ws+XPOFF;
  proj_kernel<<<dim3(256,4,1),256,0,stream>>>(pa);
  ra.xp[0]=ws+XPOFF; ra.wt[0]=whh+0*PSLOT; ra.outh[0]=(unsigned*)(ws+BUF0H);
  rec_kernel<<<dim3(32,1),512,REC_LDS,stream>>>(ra);
  // shared layer 1
  pa.K2=128; pa.x[0]=(unsigned*)(ws+BUF0H); pa.wt[0]=wih+1*PSLOT; pa.bias[0]=sb1; pa.out[0]=ws+XPOFF;
  proj_kernel<<<dim3(256,4,1),256,0,stream>>>(pa);
  ra.xp[0]=ws+XPOFF; ra.wt[0]=whh+1*PSLOT; ra.outh[0]=(unsigned*)(ws+BUF1H);
  rec_kernel<<<dim3(32,1),512,REC_LDS,stream>>>(ra);
  // shared batchnorm
  sa.in[0]=(unsigned*)(ws+BUF1H); sa.stats[0]=ws+S_BN;
  stats_kernel<<<dim3(8,1),256,0,stream>>>(sa);
  norm_kernel<<<1024,256,0,stream>>>((unsigned*)(ws+BUF1H), ws+S_BN, bsg, bsb, (unsigned*)(ws+BUFNH));
  // heads layer 0
  pa.K2=128;
  for (int hd=0;hd<3;hd++){
    pa.x[hd]=(unsigned*)(ws+BUFNH); pa.wt[hd]=wih+(size_t)(2+hd*2)*PSLOT; pa.bias[hd]=hb + (size_t)(hd*2)*G4;
    pa.out[hd]=ws+XPOFF+(size_t)hd*2097152;
  }
  proj_kernel<<<dim3(256,4,3),256,0,stream>>>(pa);
  for (int hd=0;hd<3;hd++){
    ra.xp[hd]=ws+XPOFF+(size_t)hd*2097152; ra.wt[hd]=whh+(size_t)(2+hd*2)*PSLOT;
    ra.outh[hd]=(unsigned*)(ws+HB0H)+(size_t)hd*262144;
  }
  rec_kernel<<<dim3(32,3),512,REC_LDS,stream>>>(ra);
  // heads layer 1
  for (int hd=0;hd<3;hd++){
    pa.x[hd]=(unsigned*)(ws+HB0H)+(size_t)hd*262144; pa.wt[hd]=wih+(size_t)(2+hd*2+1)*PSLOT;
    pa.bias[hd]=hb + (size_t)(hd*2+1)*G4;
    pa.out[hd]=ws+XPOFF+(size_t)hd*2097152;
  }
  proj_kernel<<<dim3(256,4,3),256,0,stream>>>(pa);
  for (int hd=0;hd<3;hd++){
    ra.xp[hd]=ws+XPOFF+(size_t)hd*2097152; ra.wt[hd]=whh+(size_t)(2+hd*2+1)*PSLOT;
    ra.outh[hd]=(unsigned*)(ws+HB1H)+(size_t)hd*262144;
  }
  rec_kernel<<<dim3(32,3),512,REC_LDS,stream>>>(ra);
  // heads batchnorm stats
  for (int hd=0;hd<3;hd++){ sa.in[hd]=(unsigned*)(ws+HB1H)+(size_t)hd*262144; sa.stats[hd]=ws+S_BN+(size_t)(1+hd)*512; }
  stats_kernel<<<dim3(8,3),256,0,stream>>>(sa);
  // final outputs
  final_kernel<<<1,256,0,stream>>>((unsigned*)(ws+HB1H), (unsigned*)(ws+HB1H)+262144, (unsigned*)(ws+HB1H)+2*262144,
                                   ws+S_BN, hbg, hbb, actW, actB, tW, tB, rW, rB, out);
}